// Round 1
// baseline (243.502 us; speedup 1.0000x reference)
//
#include <hip/hip_runtime.h>

// ---------- types ----------
typedef __attribute__((ext_vector_type(8))) _Float16 h8;
typedef __attribute__((ext_vector_type(4))) _Float16 h4;
typedef __attribute__((ext_vector_type(4))) float f32x4;

__device__ __forceinline__ _Float16 f2h(float f) { return (_Float16)f; }
__device__ __forceinline__ float h2f(_Float16 h) { return (float)h; }

// swizzled element index into feat LDS tile [px][128] (XOR of i bits 3..5 with px&7)
__device__ __forceinline__ int fswz(int p, int i) { return p * 128 + (i ^ ((p & 7) << 3)); }

// ---------- ws layout (bytes) ----------
#define WS_STA   0u          // _Float16 [4*64*96*96]            4718592 B
#define WS_GSI   4718592u    // int   [4][4]  {dx,dy,sdx,sdy}
#define WS_GSF   4718656u    // float [4][4]  {wx1,wy1,swx1,swy1}
#define WS_WCPX  4718720u    // float [4][8][64]
#define WS_WEPX  4726912u    // float [4][64][8]
#define WS_FUSB  4735104u    // _Float16 [4][4][64][8]  (fusion B fragments)
#define WS_KCB   4751488u    // float [1600] permuted bias
#define WS_KCW   4757888u    // _Float16 [1600][64] permuted kc_w

// =====================================================================
// k_prep: permute+convert kc_w -> f16 (j' = w*400 + t*16 + cl), permuted
// bias, and fusion-weight B-fragments.
// =====================================================================
__global__ __launch_bounds__(256) void k_prep(
    const float* __restrict__ kc_w, const float* __restrict__ kc_b,
    const float* __restrict__ fusw,
    _Float16* __restrict__ kcw, _Float16* __restrict__ fusB,
    float* __restrict__ kcbp)
{
  int e = blockIdx.x * 256 + threadIdx.x;
  if (e < 25600) {
    int jp = e >> 4, i0 = (e & 15) << 2;
    int w = jp / 400, rem = jp % 400;
    int t = rem >> 4, cl = rem & 15;
    int j = (w * 16 + cl) * 25 + t;           // original row: channel-major c*25+t
    const float4* src = (const float4*)(kc_w + j * 64 + i0);
    float4 v = *src;
    h4 ov;
    ov[0] = f2h(v.x); ov[1] = f2h(v.y); ov[2] = f2h(v.z); ov[3] = f2h(v.w);
    *(h4*)(kcw + jp * 64 + i0) = ov;
  }
  if (e < 8192) {
    // fusB[Nt][ks][lane][j] = fus_w[(Nt*16 + (l&15))*128 + (l>>4)*8 + 32*ks + j]
    int Nt = e >> 11, ks = (e >> 9) & 3, l = (e >> 3) & 63, j = e & 7;
    fusB[e] = f2h(fusw[(Nt * 16 + (l & 15)) * 128 + (l >> 4) * 8 + 32 * ks + j]);
  }
  if (e < 1600) {
    int w = e / 400, rem = e % 400, t = rem >> 4, cl = rem & 15;
    kcbp[e] = kc_b[(w * 16 + cl) * 25 + t];
  }
}

// =====================================================================
// k_embed: the 4 parity variants of the coordinate embedding ->
// grid-sample tables + combined MoE weights.
// =====================================================================
__global__ __launch_bounds__(256) void k_embed(
    const float* __restrict__ b1w, const float* __restrict__ b1b,
    const float* __restrict__ b2w, const float* __restrict__ b2b,
    const float* __restrict__ rw,  const float* __restrict__ rb,
    const float* __restrict__ ow,  const float* __restrict__ ob,
    const float* __restrict__ sow, const float* __restrict__ sob,
    const float* __restrict__ wc,  const float* __restrict__ we,
    int* __restrict__ gs_i, float* __restrict__ gs_f,
    float* __restrict__ wcpx, float* __restrict__ wepx)
{
  __shared__ float l_w2[4096];
  __shared__ float l_h1[4][64];
  __shared__ float l_h2[4][64];
  __shared__ float l_sm[4][8];
  int tid = threadIdx.x;
  for (int e = tid; e < 4096; e += 256) l_w2[e] = b2w[e];
  int g = tid >> 6, o = tid & 63;
  float py = (g >> 1) ? 1.f : 0.f;
  float pxx = (g & 1) ? 1.f : 0.f;
  float chh = (py + 0.5f) * 0.5f;
  float coh = chh - floorf(chh + 0.001f) - 0.5f;
  float cww = (pxx + 0.5f) * 0.5f;
  float cow = cww - floorf(cww + 0.001f) - 0.5f;
  float z = b1b[o] + b1w[o * 4 + 0] * 0.5f + b1w[o * 4 + 1] * 0.5f
          + b1w[o * 4 + 2] * coh + b1w[o * 4 + 3] * cow;
  l_h1[g][o] = fmaxf(z, 0.f);
  __syncthreads();
  float z2 = b2b[o];
  #pragma unroll 8
  for (int i = 0; i < 64; i++) z2 = fmaf(l_w2[o * 64 + i], l_h1[g][i], z2);
  l_h2[g][o] = fmaxf(z2, 0.f);
  __syncthreads();
  if (o < 8) {
    const float* wp; float bias;
    if (o < 4)      { wp = rw  + o * 64;       bias = rb[o]; }
    else if (o < 6) { wp = ow  + (o - 4) * 64; bias = ob[o - 4]; }
    else            { wp = sow + (o - 6) * 64; bias = sob[o - 6]; }
    float acc = bias;
    for (int i = 0; i < 64; i++) acc = fmaf(wp[i], l_h2[g][i], acc);
    if (o < 4) acc = 1.f / (1.f + expf(-acc));
    l_sm[g][o] = acc;
  }
  __syncthreads();
  if (o == 0) {
    float qbx = (g & 1) ? 0.25f : -0.25f;
    float qby = (g >> 1) ? 0.25f : -0.25f;
    float qx  = qbx + l_sm[g][4]; float fx  = floorf(qx);
    float qy  = qby + l_sm[g][5]; float fy  = floorf(qy);
    float qsx = qbx + l_sm[g][6]; float fsx = floorf(qsx);
    float qsy = qby + l_sm[g][7]; float fsy = floorf(qsy);
    gs_i[g * 4 + 0] = (int)fx;  gs_f[g * 4 + 0] = qx - fx;
    gs_i[g * 4 + 1] = (int)fy;  gs_f[g * 4 + 1] = qy - fy;
    gs_i[g * 4 + 2] = (int)fsx; gs_f[g * 4 + 2] = qsx - fsx;
    gs_i[g * 4 + 3] = (int)fsy; gs_f[g * 4 + 3] = qsy - fsy;
  }
  float r0 = l_sm[g][0], r1 = l_sm[g][1], r2 = l_sm[g][2], r3 = l_sm[g][3];
  for (int idx = o; idx < 512; idx += 64) {
    wcpx[g * 512 + idx] = r0 * wc[idx] + r1 * wc[512 + idx] + r2 * wc[1024 + idx] + r3 * wc[1536 + idx];
    wepx[g * 512 + idx] = r0 * we[idx] + r1 * we[512 + idx] + r2 * we[1024 + idx] + r3 * we[1536 + idx];
  }
}

// =====================================================================
// k_sta: fused kernel_warp (f16 MFMA GEMM) + 5x5 spatially-varying conv.
// WG = 256 thr (4 waves), 32-pixel tile (1 row x 32 cols).
// Wave w owns channels [w*16, w*16+16) == permuted j' range [w*400, w*400+400).
// j-tile (16 outputs) == one tap t for all 16 channels (permuted layout),
// so sta accumulators are statically indexed. No inter-wave kw sharing.
// =====================================================================
__global__ __launch_bounds__(256) void k_sta(
    const float* __restrict__ x, const float* __restrict__ st,
    const _Float16* __restrict__ kcw, const float* __restrict__ kcbp,
    _Float16* __restrict__ sta_out)
{
  __shared__ __align__(16) _Float16 x_lds[64 * 5 * 37];   // [c][row 0..4][col 0..36]
  __shared__ __align__(16) _Float16 kw_lds[4 * 5 * 16 * 34]; // [w][dw][cl][px(+pad)]
  int wg = blockIdx.x;
  int b = wg / 288;
  int r1 = wg % 288;
  int hb = r1 / 3, wb = r1 % 3;
  int tid = threadIdx.x, lane = tid & 63, w = tid >> 6;
  // stage x tile with replicate clamp (5 rows x 36 cols x 64 ch)
  for (int e = tid; e < 64 * 5 * 36; e += 256) {
    int c = e / 180, rr = (e % 180) / 36, col = e % 36;
    int grow = min(max(hb + rr - 2, 0), 95);
    int gcol = min(max(32 * wb + col - 2, 0), 95);
    x_lds[(c * 5 + rr) * 37 + col] = f2h(x[((b * 64 + c) * 96 + grow) * 96 + gcol]);
  }
  // A fragments: 2 M-subtiles x 2 k-steps (st_feat pixels, K=64 channels)
  int l15 = lane & 15, lg = lane >> 4;
  h8 afrag[2][2];
  #pragma unroll
  for (int ms = 0; ms < 2; ms++) {
    int col = 32 * wb + ms * 16 + l15;
    const float* sp = st + ((size_t)b * 64 * 96 + hb) * 96 + col;
    #pragma unroll
    for (int ks = 0; ks < 2; ks++) {
      h8 f;
      #pragma unroll
      for (int j = 0; j < 8; j++) {
        int i = 32 * ks + lg * 8 + j;
        f[j] = f2h(sp[i * 9216]);
      }
      afrag[ms][ks] = f;
    }
  }
  __syncthreads();
  float sta_acc[8];
  #pragma unroll
  for (int q = 0; q < 8; q++) sta_acc[q] = 0.f;
  int pxl = lane & 31, half = lane >> 5;
  for (int dh = 0; dh < 5; dh++) {
    // ---- phase A: 5 taps (dw=0..4), each = one 16x16 j-tile per wave ----
    #pragma unroll
    for (int dw = 0; dw < 5; dw++) {
      int t = dh * 5 + dw;
      int jbase = w * 400 + t * 16;
      const _Float16* bp = kcw + (jbase + l15) * 64 + lg * 8;
      h8 bf0 = *(const h8*)bp;
      h8 bf1 = *(const h8*)(bp + 32);
      float kb = kcbp[jbase + l15];
      #pragma unroll
      for (int ms = 0; ms < 2; ms++) {
        f32x4 acc = {0.f, 0.f, 0.f, 0.f};
        acc = __builtin_amdgcn_mfma_f32_16x16x32_f16(afrag[ms][0], bf0, acc, 0, 0, 0);
        acc = __builtin_amdgcn_mfma_f32_16x16x32_f16(afrag[ms][1], bf1, acc, 0, 0, 0);
        h4 pk;
        #pragma unroll
        for (int rr = 0; rr < 4; rr++) {
          float zz = acc[rr] + kb;
          zz = (zz >= 0.f) ? zz : 0.1f * zz;     // leaky_relu 0.1
          pk[rr] = f2h(zz);
        }
        // D: col=l15 -> channel-local, row=lg*4+reg -> pixel
        *(h4*)&kw_lds[((w * 5 + dw) * 16 + l15) * 34 + ms * 16 + lg * 4] = pk;
      }
    }
    // ---- phase B: accumulate sta (lane = (half, pxl); 8 channels each) ----
    #pragma unroll
    for (int dw = 0; dw < 5; dw++) {
      const _Float16* kwp = &kw_lds[((w * 5 + dw) * 16) * 34 + pxl];
      const _Float16* xp2 = &x_lds[((w * 16 + half * 8) * 5 + dh) * 37 + pxl + dw];
      #pragma unroll
      for (int q = 0; q < 8; q++) {
        float kwv = h2f(kwp[(half * 8 + q) * 34]);
        float xv  = h2f(xp2[q * 185]);   // 5*37 channel stride
        sta_acc[q] = fmaf(kwv, xv, sta_acc[q]);
      }
    }
  }
  #pragma unroll
  for (int q = 0; q < 8; q++) {
    int c = w * 16 + half * 8 + q;
    sta_out[((b * 64 + c) * 96 + hb) * 96 + 32 * wb + pxl] = f2h(sta_acc[q]);
  }
}

// =====================================================================
// k_main: per 64-pixel HR row chunk: grid samples (parity-table stencils),
// MoE (precombined weights, scalar-load), fusion conv via f16 MFMA.
// =====================================================================
__global__ __launch_bounds__(256) void k_main(
    const float* __restrict__ x, const _Float16* __restrict__ sta,
    const int* __restrict__ gs_i, const float* __restrict__ gs_f,
    const float* __restrict__ wcpx, const float* __restrict__ wepx,
    const _Float16* __restrict__ fusB, const float* __restrict__ fusb,
    float* __restrict__ out)
{
  __shared__ __align__(16) _Float16 feat[64 * 128]; // swizzled [px][0:64 sta_hr | 64:128 fea0->fea]
  __shared__ float t_lds[8][68];
  int wg = blockIdx.x;
  int b = wg / 576, r = wg % 576;
  int y = r / 3, xb = r % 3;
  int tid = threadIdx.x, px = tid & 63, fg = tid >> 6;
  int xg = xb * 64 + px;
  int v = ((y & 1) << 1) | (xg & 1);
  int idxo = gs_i[v * 4 + 0], idyo = gs_i[v * 4 + 1], idxs = gs_i[v * 4 + 2], idys = gs_i[v * 4 + 3];
  float wx1 = gs_f[v * 4 + 0], wy1 = gs_f[v * 4 + 1], sx1 = gs_f[v * 4 + 2], sy1 = gs_f[v * 4 + 3];
  int xh = xg >> 1, yh = y >> 1;
  // offset path (fea0 from x)
  int ix0 = xh + idxo, iy0 = yh + idyo;
  float wx0 = 1.f - wx1, wy0 = 1.f - wy1;
  bool vx0 = (unsigned)ix0 < 96u, vx1 = (unsigned)(ix0 + 1) < 96u;
  bool vy0 = (unsigned)iy0 < 96u, vy1 = (unsigned)(iy0 + 1) < 96u;
  int cx0 = min(max(ix0, 0), 95), cx1 = min(max(ix0 + 1, 0), 95);
  int cy0 = min(max(iy0, 0), 95), cy1 = min(max(iy0 + 1, 0), 95);
  float ww00 = (vx0 && vy0) ? wy0 * wx0 : 0.f;
  float ww10 = (vx1 && vy0) ? wy0 * wx1 : 0.f;
  float ww01 = (vx0 && vy1) ? wy1 * wx0 : 0.f;
  float ww11 = (vx1 && vy1) ? wy1 * wx1 : 0.f;
  int a00 = cy0 * 96 + cx0, a10 = cy0 * 96 + cx1, a01 = cy1 * 96 + cx0, a11 = cy1 * 96 + cx1;
  // st_offset path (sta_hr from sta_feat)
  int jx0 = xh + idxs, jy0 = yh + idys;
  float sx0 = 1.f - sx1, sy0 = 1.f - sy1;
  bool ux0 = (unsigned)jx0 < 96u, ux1 = (unsigned)(jx0 + 1) < 96u;
  bool uy0 = (unsigned)jy0 < 96u, uy1 = (unsigned)(jy0 + 1) < 96u;
  int dx0 = min(max(jx0, 0), 95), dx1 = min(max(jx0 + 1, 0), 95);
  int dy0 = min(max(jy0, 0), 95), dy1 = min(max(jy0 + 1, 0), 95);
  float sw00 = (ux0 && uy0) ? sy0 * sx0 : 0.f;
  float sw10 = (ux1 && uy0) ? sy0 * sx1 : 0.f;
  float sw01 = (ux0 && uy1) ? sy1 * sx0 : 0.f;
  float sw11 = (ux1 && uy1) ? sy1 * sx1 : 0.f;
  int s00 = dy0 * 96 + dx0, s10 = dy0 * 96 + dx1, s01 = dy1 * 96 + dx0, s11 = dy1 * 96 + dx1;
  // ---- P1: gather sta_hr + fea0, 16 channels per thread-group ----
  h8 stv0, stv1, fev0, fev1;
  #pragma unroll
  for (int k = 0; k < 16; k++) {
    int ch = fg * 16 + k;
    const float* xc = x + (size_t)(b * 64 + ch) * 9216;
    float f0 = ww00 * xc[a00] + ww10 * xc[a10] + ww01 * xc[a01] + ww11 * xc[a11];
    const _Float16* sc = sta + (size_t)(b * 64 + ch) * 9216;
    float s0 = sw00 * h2f(sc[s00]) + sw10 * h2f(sc[s10]) + sw01 * h2f(sc[s01]) + sw11 * h2f(sc[s11]);
    if (k < 8) { stv0[k] = f2h(s0); fev0[k] = f2h(f0); }
    else       { stv1[k - 8] = f2h(s0); fev1[k - 8] = f2h(f0); }
  }
  *(h8*)&feat[fswz(px, fg * 16)]          = stv0;
  *(h8*)&feat[fswz(px, fg * 16 + 8)]      = stv1;
  *(h8*)&feat[fswz(px, 64 + fg * 16)]     = fev0;
  *(h8*)&feat[fswz(px, 64 + fg * 16 + 8)] = fev1;
  __syncthreads();
  // ---- P2: t[o] = wcpx[v] . fea0 (both row-variants, select by x parity) ----
  {
    int o2 = fg * 2;
    int v0 = (y & 1) << 1;
    int base = __builtin_amdgcn_readfirstlane((v0 * 8 + o2) * 64);
    const float* w00 = wcpx + base;
    const float* w01 = wcpx + base + 64;
    const float* w10 = wcpx + base + 512;
    const float* w11 = wcpx + base + 512 + 64;
    float acc00 = 0.f, acc01 = 0.f, acc10 = 0.f, acc11 = 0.f;
    #pragma unroll
    for (int cb = 0; cb < 8; cb++) {
      h8 blk = *(const h8*)&feat[fswz(px, 64 + cb * 8)];
      #pragma unroll
      for (int q = 0; q < 8; q++) {
        float fv = h2f(blk[q]);
        int c = cb * 8 + q;
        acc00 = fmaf(w00[c], fv, acc00);
        acc01 = fmaf(w01[c], fv, acc01);
        acc10 = fmaf(w10[c], fv, acc10);
        acc11 = fmaf(w11[c], fv, acc11);
      }
    }
    bool odd = (xg & 1);
    t_lds[o2][px]     = odd ? acc10 : acc00;
    t_lds[o2 + 1][px] = odd ? acc11 : acc01;
  }
  __syncthreads();
  // ---- P3: fea = fea0 + wepx[v] @ t (overwrite fea0 slots) ----
  {
    float tv[8];
    #pragma unroll
    for (int oo = 0; oo < 8; oo++) tv[oo] = t_lds[oo][px];
    int v0 = (y & 1) << 1;
    bool odd = (xg & 1);
    int wbase = __builtin_amdgcn_readfirstlane((v0 * 64 + fg * 16) * 8);
    #pragma unroll
    for (int blki = 0; blki < 2; blki++) {
      h8 f0b = *(const h8*)&feat[fswz(px, 64 + fg * 16 + blki * 8)];
      h8 ob2;
      #pragma unroll
      for (int q = 0; q < 8; q++) {
        int k = blki * 8 + q;
        const float* wA = wepx + wbase + k * 8;
        const float* wB = wA + 512;
        float sA = 0.f, sB = 0.f;
        #pragma unroll
        for (int oo = 0; oo < 8; oo++) { sA = fmaf(wA[oo], tv[oo], sA); sB = fmaf(wB[oo], tv[oo], sB); }
        float fe = h2f(f0b[q]) + (odd ? sB : sA);
        ob2[q] = f2h(fe);
      }
      *(h8*)&feat[fswz(px, 64 + fg * 16 + blki * 8)] = ob2;
    }
  }
  __syncthreads();
  // ---- P4: fusion conv via MFMA: [64px x 128] @ [128 x 64] ----
  {
    int l15 = px & 15, lg = px >> 4;
    h8 af[4];
    #pragma unroll
    for (int ks = 0; ks < 4; ks++)
      af[ks] = *(const h8*)&feat[fswz(fg * 16 + l15, lg * 8 + 32 * ks)];
    #pragma unroll
    for (int Nt = 0; Nt < 4; Nt++) {
      f32x4 acc = {0.f, 0.f, 0.f, 0.f};
      #pragma unroll
      for (int ks = 0; ks < 4; ks++) {
        h8 bfv = *(const h8*)&fusB[((Nt * 4 + ks) * 64 + px) * 8];
        acc = __builtin_amdgcn_mfma_f32_16x16x32_f16(af[ks], bfv, acc, 0, 0, 0);
      }
      int c = Nt * 16 + l15;
      float bias = fusb[c];
      float4 o4;
      o4.x = acc[0] + bias; o4.y = acc[1] + bias; o4.z = acc[2] + bias; o4.w = acc[3] + bias;
      float* op = out + ((size_t)(b * 64 + c) * 192 + y) * 192 + xb * 64 + fg * 16 + lg * 4;
      *(float4*)op = o4;
    }
  }
}

// =====================================================================
extern "C" void kernel_launch(void* const* d_in, const int* in_sizes, int n_in,
                              void* d_out, int out_size, void* d_ws, size_t ws_size,
                              hipStream_t stream)
{
  (void)in_sizes; (void)n_in; (void)out_size; (void)ws_size;
  const float* x    = (const float*)d_in[0];
  const float* st   = (const float*)d_in[1];
  const float* kc_w = (const float*)d_in[2];
  const float* kc_b = (const float*)d_in[3];
  const float* wc   = (const float*)d_in[4];
  const float* we   = (const float*)d_in[5];
  const float* b1w  = (const float*)d_in[6];
  const float* b1b  = (const float*)d_in[7];
  const float* b2w  = (const float*)d_in[8];
  const float* b2b  = (const float*)d_in[9];
  const float* rw   = (const float*)d_in[10];
  const float* rb   = (const float*)d_in[11];
  const float* ow   = (const float*)d_in[12];
  const float* ob   = (const float*)d_in[13];
  const float* sow  = (const float*)d_in[14];
  const float* sob  = (const float*)d_in[15];
  const float* fusw = (const float*)d_in[16];
  const float* fusb = (const float*)d_in[17];
  char* ws = (char*)d_ws;
  _Float16* sta  = (_Float16*)(ws + WS_STA);
  int*   gsi  = (int*)(ws + WS_GSI);
  float* gsf  = (float*)(ws + WS_GSF);
  float* wcpxp = (float*)(ws + WS_WCPX);
  float* wepxp = (float*)(ws + WS_WEPX);
  _Float16* fusB = (_Float16*)(ws + WS_FUSB);
  float* kcbp = (float*)(ws + WS_KCB);
  _Float16* kcw = (_Float16*)(ws + WS_KCW);
  float* outp = (float*)d_out;

  k_prep<<<dim3(100), dim3(256), 0, stream>>>(kc_w, kc_b, fusw, kcw, fusB, kcbp);
  k_embed<<<dim3(1), dim3(256), 0, stream>>>(b1w, b1b, b2w, b2b, rw, rb, ow, ob,
                                             sow, sob, wc, we, gsi, gsf, wcpxp, wepxp);
  k_sta<<<dim3(1152), dim3(256), 0, stream>>>(x, st, kcw, kcbp, sta);
  k_main<<<dim3(2304), dim3(256), 0, stream>>>(x, sta, gsi, gsf, wcpxp, wepxp, fusB, fusb, outp);
}

// Round 2
// 213.652 us; speedup vs baseline: 1.1397x; 1.1397x over previous
//
#include <hip/hip_runtime.h>

// ---------- types ----------
typedef __attribute__((ext_vector_type(8))) _Float16 h8;
typedef __attribute__((ext_vector_type(4))) _Float16 h4;
typedef __attribute__((ext_vector_type(4))) float f32x4;

__device__ __forceinline__ _Float16 f2h(float f) { return (_Float16)f; }
__device__ __forceinline__ float h2f(_Float16 h) { return (float)h; }

// swizzled element index into feat LDS tile [px][128] (XOR of i bits 3..5 with px&7)
__device__ __forceinline__ int fswz(int p, int i) { return p * 128 + (i ^ ((p & 7) << 3)); }

// ---------- ws layout (bytes) ----------
#define WS_STA   0u          // _Float16 [4*64*96*96]            4718592 B
#define WS_GSI   4718592u    // int   [4][4]  {dx,dy,sdx,sdy}
#define WS_GSF   4718656u    // float [4][4]  {wx1,wy1,swx1,swy1}
#define WS_WCPX  4718720u    // float [4][8][64]
#define WS_WEPX  4726912u    // float [4][64][8]
#define WS_FUSB  4735104u    // _Float16 [4][4][64][8]  (fusion B fragments)
#define WS_KCB   4751488u    // float [1600] permuted bias
#define WS_KCW   4757888u    // _Float16 [1600][64] permuted kc_w

// =====================================================================
// k_prep: permute+convert kc_w -> f16 (j' = w*400 + t*16 + cl), permuted
// bias, and fusion-weight B-fragments.
// =====================================================================
__global__ __launch_bounds__(256) void k_prep(
    const float* __restrict__ kc_w, const float* __restrict__ kc_b,
    const float* __restrict__ fusw,
    _Float16* __restrict__ kcw, _Float16* __restrict__ fusB,
    float* __restrict__ kcbp)
{
  int e = blockIdx.x * 256 + threadIdx.x;
  if (e < 25600) {
    int jp = e >> 4, i0 = (e & 15) << 2;
    int w = jp / 400, rem = jp % 400;
    int t = rem >> 4, cl = rem & 15;
    int j = (w * 16 + cl) * 25 + t;           // original row: channel-major c*25+t
    const float4* src = (const float4*)(kc_w + j * 64 + i0);
    float4 v = *src;
    h4 ov;
    ov[0] = f2h(v.x); ov[1] = f2h(v.y); ov[2] = f2h(v.z); ov[3] = f2h(v.w);
    *(h4*)(kcw + jp * 64 + i0) = ov;
  }
  if (e < 8192) {
    // fusB[Nt][ks][lane][j] = fus_w[(Nt*16 + (l&15))*128 + (l>>4)*8 + 32*ks + j]
    int Nt = e >> 11, ks = (e >> 9) & 3, l = (e >> 3) & 63, j = e & 7;
    fusB[e] = f2h(fusw[(Nt * 16 + (l & 15)) * 128 + (l >> 4) * 8 + 32 * ks + j]);
  }
  if (e < 1600) {
    int w = e / 400, rem = e % 400, t = rem >> 4, cl = rem & 15;
    kcbp[e] = kc_b[(w * 16 + cl) * 25 + t];
  }
}

// =====================================================================
// k_embed: the 4 parity variants of the coordinate embedding ->
// grid-sample tables + combined MoE weights.
// =====================================================================
__global__ __launch_bounds__(256) void k_embed(
    const float* __restrict__ b1w, const float* __restrict__ b1b,
    const float* __restrict__ b2w, const float* __restrict__ b2b,
    const float* __restrict__ rw,  const float* __restrict__ rb,
    const float* __restrict__ ow,  const float* __restrict__ ob,
    const float* __restrict__ sow, const float* __restrict__ sob,
    const float* __restrict__ wc,  const float* __restrict__ we,
    int* __restrict__ gs_i, float* __restrict__ gs_f,
    float* __restrict__ wcpx, float* __restrict__ wepx)
{
  __shared__ float l_w2[4096];
  __shared__ float l_h1[4][64];
  __shared__ float l_h2[4][64];
  __shared__ float l_sm[4][8];
  int tid = threadIdx.x;
  for (int e = tid; e < 4096; e += 256) l_w2[e] = b2w[e];
  int g = tid >> 6, o = tid & 63;
  float py = (g >> 1) ? 1.f : 0.f;
  float pxx = (g & 1) ? 1.f : 0.f;
  float chh = (py + 0.5f) * 0.5f;
  float coh = chh - floorf(chh + 0.001f) - 0.5f;
  float cww = (pxx + 0.5f) * 0.5f;
  float cow = cww - floorf(cww + 0.001f) - 0.5f;
  float z = b1b[o] + b1w[o * 4 + 0] * 0.5f + b1w[o * 4 + 1] * 0.5f
          + b1w[o * 4 + 2] * coh + b1w[o * 4 + 3] * cow;
  l_h1[g][o] = fmaxf(z, 0.f);
  __syncthreads();
  float z2 = b2b[o];
  #pragma unroll 8
  for (int i = 0; i < 64; i++) z2 = fmaf(l_w2[o * 64 + i], l_h1[g][i], z2);
  l_h2[g][o] = fmaxf(z2, 0.f);
  __syncthreads();
  if (o < 8) {
    const float* wp; float bias;
    if (o < 4)      { wp = rw  + o * 64;       bias = rb[o]; }
    else if (o < 6) { wp = ow  + (o - 4) * 64; bias = ob[o - 4]; }
    else            { wp = sow + (o - 6) * 64; bias = sob[o - 6]; }
    float acc = bias;
    for (int i = 0; i < 64; i++) acc = fmaf(wp[i], l_h2[g][i], acc);
    if (o < 4) acc = 1.f / (1.f + expf(-acc));
    l_sm[g][o] = acc;
  }
  __syncthreads();
  if (o == 0) {
    float qbx = (g & 1) ? 0.25f : -0.25f;
    float qby = (g >> 1) ? 0.25f : -0.25f;
    float qx  = qbx + l_sm[g][4]; float fx  = floorf(qx);
    float qy  = qby + l_sm[g][5]; float fy  = floorf(qy);
    float qsx = qbx + l_sm[g][6]; float fsx = floorf(qsx);
    float qsy = qby + l_sm[g][7]; float fsy = floorf(qsy);
    gs_i[g * 4 + 0] = (int)fx;  gs_f[g * 4 + 0] = qx - fx;
    gs_i[g * 4 + 1] = (int)fy;  gs_f[g * 4 + 1] = qy - fy;
    gs_i[g * 4 + 2] = (int)fsx; gs_f[g * 4 + 2] = qsx - fsx;
    gs_i[g * 4 + 3] = (int)fsy; gs_f[g * 4 + 3] = qsy - fsy;
  }
  float r0 = l_sm[g][0], r1 = l_sm[g][1], r2 = l_sm[g][2], r3 = l_sm[g][3];
  for (int idx = o; idx < 512; idx += 64) {
    wcpx[g * 512 + idx] = r0 * wc[idx] + r1 * wc[512 + idx] + r2 * wc[1024 + idx] + r3 * wc[1536 + idx];
    wepx[g * 512 + idx] = r0 * we[idx] + r1 * we[512 + idx] + r2 * we[1024 + idx] + r3 * we[1536 + idx];
  }
}

// =====================================================================
// k_sta: fused kernel_warp (f16 MFMA GEMM) + 5x5 spatially-varying conv.
// WG = 256 thr (4 waves), 32-pixel tile (1 row x 32 cols).
// Wave w owns channels [w*16, w*16+16) via permuted kcw (j' = w*400+t*16+cl).
// The MFMA D fragment for tap t leaves kw[c=w*16+l15][px=ms*16+lg*4+r] in
// lane registers -> the depthwise conv consumes it directly; only x goes
// through LDS (2 aligned ds_read_b64 per ms per dh). No kw LDS round-trip.
// =====================================================================
__global__ __launch_bounds__(256, 4) void k_sta(
    const float* __restrict__ x, const float* __restrict__ st,
    const _Float16* __restrict__ kcw, const float* __restrict__ kcbp,
    _Float16* __restrict__ sta_out)
{
  __shared__ __align__(16) _Float16 x_lds[64 * 5 * 40];   // [c][row 0..4][col 0..35 (+pad)]
  int wg = blockIdx.x;
  int b = wg / 288;
  int r1 = wg % 288;
  int hb = r1 / 3, wb = r1 % 3;
  int tid = threadIdx.x, lane = tid & 63, w = tid >> 6;
  // ---- stage x tile (5 rows x 36 cols x 64 ch), float4 interior + scalar edges ----
  // local col i <-> global col 32*wb + i - 2 (replicate-clamped)
  for (int e = tid; e < 2560; e += 256) {           // interior: cols 2..33
    int row = e >> 3, v = e & 7;                    // row = c*5+rr
    int rr = row % 5;
    int grow = min(max(hb + rr - 2, 0), 95);
    float4 val = *(const float4*)&x[((b * 64 + (row / 5)) * 96 + grow) * 96 + 32 * wb + v * 4];
    _Float16* dst = &x_lds[row * 40 + 2 + v * 4];
    dst[0] = f2h(val.x); dst[1] = f2h(val.y); dst[2] = f2h(val.z); dst[3] = f2h(val.w);
  }
  for (int e = tid; e < 1280; e += 256) {           // edges: cols 0,1,34,35
    int row = e >> 2, j = e & 3;
    int col = (j < 2) ? j : 32 + j;
    int rr = row % 5;
    int grow = min(max(hb + rr - 2, 0), 95);
    int gcol = min(max(32 * wb + col - 2, 0), 95);
    x_lds[row * 40 + col] = f2h(x[((b * 64 + (row / 5)) * 96 + grow) * 96 + gcol]);
  }
  // ---- A fragments: 2 M-subtiles x 2 k-steps (st_feat pixels, K=64 channels) ----
  int l15 = lane & 15, lg = lane >> 4;
  h8 afrag[2][2];
  #pragma unroll
  for (int ms = 0; ms < 2; ms++) {
    int col = 32 * wb + ms * 16 + l15;
    const float* sp = st + ((size_t)b * 64 * 96 + hb) * 96 + col;
    #pragma unroll
    for (int ks = 0; ks < 2; ks++) {
      h8 f;
      #pragma unroll
      for (int j = 0; j < 8; j++) {
        int i = 32 * ks + lg * 8 + j;
        f[j] = f2h(sp[i * 9216]);
      }
      afrag[ms][ks] = f;
    }
  }
  __syncthreads();
  // ---- main loop: per tap, MFMA kw (stays in regs) -> conv accumulate ----
  float sta_acc[2][4];
  #pragma unroll
  for (int ms = 0; ms < 2; ms++)
    #pragma unroll
    for (int r = 0; r < 4; r++) sta_acc[ms][r] = 0.f;
  for (int dh = 0; dh < 5; dh++) {
    h4 xa[2][2];   // per ms: 8 contiguous h16 at cols [ms*16+lg*4 .. +7]
    #pragma unroll
    for (int ms = 0; ms < 2; ms++) {
      const _Float16* xp = &x_lds[((w * 16 + l15) * 5 + dh) * 40 + ms * 16 + lg * 4];
      xa[ms][0] = *(const h4*)xp;
      xa[ms][1] = *(const h4*)(xp + 4);
    }
    #pragma unroll
    for (int dw = 0; dw < 5; dw++) {
      int jbase = w * 400 + (dh * 5 + dw) * 16;
      const _Float16* bp = kcw + (jbase + l15) * 64 + lg * 8;
      h8 bf0 = *(const h8*)bp;
      h8 bf1 = *(const h8*)(bp + 32);
      float kb = kcbp[jbase + l15];
      #pragma unroll
      for (int ms = 0; ms < 2; ms++) {
        f32x4 acc = {0.f, 0.f, 0.f, 0.f};
        acc = __builtin_amdgcn_mfma_f32_16x16x32_f16(afrag[ms][0], bf0, acc, 0, 0, 0);
        acc = __builtin_amdgcn_mfma_f32_16x16x32_f16(afrag[ms][1], bf1, acc, 0, 0, 0);
        #pragma unroll
        for (int r = 0; r < 4; r++) {
          float kw = acc[r] + kb;
          kw = (kw >= 0.f) ? kw : 0.1f * kw;      // leaky_relu 0.1 (kw stays f32)
          int ci = r + dw;                        // static after unroll
          float xvf = h2f(ci < 4 ? xa[ms][0][ci] : xa[ms][1][ci - 4]);
          sta_acc[ms][r] = fmaf(kw, xvf, sta_acc[ms][r]);
        }
      }
    }
  }
  // ---- write out: c = w*16+l15, px = 32*wb + ms*16 + lg*4 + r (h4 stores) ----
  _Float16* op = sta_out + ((size_t)(b * 64 + w * 16 + l15) * 96 + hb) * 96 + 32 * wb;
  #pragma unroll
  for (int ms = 0; ms < 2; ms++) {
    h4 ov;
    #pragma unroll
    for (int r = 0; r < 4; r++) ov[r] = f2h(sta_acc[ms][r]);
    *(h4*)(op + ms * 16 + lg * 4) = ov;
  }
}

// =====================================================================
// k_main: per 64-pixel HR row chunk: grid samples (parity-table stencils),
// MoE (precombined weights, scalar-load), fusion conv via f16 MFMA.
// =====================================================================
__global__ __launch_bounds__(256) void k_main(
    const float* __restrict__ x, const _Float16* __restrict__ sta,
    const int* __restrict__ gs_i, const float* __restrict__ gs_f,
    const float* __restrict__ wcpx, const float* __restrict__ wepx,
    const _Float16* __restrict__ fusB, const float* __restrict__ fusb,
    float* __restrict__ out)
{
  __shared__ __align__(16) _Float16 feat[64 * 128]; // swizzled [px][0:64 sta_hr | 64:128 fea0->fea]
  __shared__ float t_lds[8][68];
  int wg = blockIdx.x;
  int b = wg / 576, r = wg % 576;
  int y = r / 3, xb = r % 3;
  int tid = threadIdx.x, px = tid & 63, fg = tid >> 6;
  int xg = xb * 64 + px;
  int v = ((y & 1) << 1) | (xg & 1);
  int idxo = gs_i[v * 4 + 0], idyo = gs_i[v * 4 + 1], idxs = gs_i[v * 4 + 2], idys = gs_i[v * 4 + 3];
  float wx1 = gs_f[v * 4 + 0], wy1 = gs_f[v * 4 + 1], sx1 = gs_f[v * 4 + 2], sy1 = gs_f[v * 4 + 3];
  int xh = xg >> 1, yh = y >> 1;
  // offset path (fea0 from x)
  int ix0 = xh + idxo, iy0 = yh + idyo;
  float wx0 = 1.f - wx1, wy0 = 1.f - wy1;
  bool vx0 = (unsigned)ix0 < 96u, vx1 = (unsigned)(ix0 + 1) < 96u;
  bool vy0 = (unsigned)iy0 < 96u, vy1 = (unsigned)(iy0 + 1) < 96u;
  int cx0 = min(max(ix0, 0), 95), cx1 = min(max(ix0 + 1, 0), 95);
  int cy0 = min(max(iy0, 0), 95), cy1 = min(max(iy0 + 1, 0), 95);
  float ww00 = (vx0 && vy0) ? wy0 * wx0 : 0.f;
  float ww10 = (vx1 && vy0) ? wy0 * wx1 : 0.f;
  float ww01 = (vx0 && vy1) ? wy1 * wx0 : 0.f;
  float ww11 = (vx1 && vy1) ? wy1 * wx1 : 0.f;
  int a00 = cy0 * 96 + cx0, a10 = cy0 * 96 + cx1, a01 = cy1 * 96 + cx0, a11 = cy1 * 96 + cx1;
  // st_offset path (sta_hr from sta_feat)
  int jx0 = xh + idxs, jy0 = yh + idys;
  float sx0 = 1.f - sx1, sy0 = 1.f - sy1;
  bool ux0 = (unsigned)jx0 < 96u, ux1 = (unsigned)(jx0 + 1) < 96u;
  bool uy0 = (unsigned)jy0 < 96u, uy1 = (unsigned)(jy0 + 1) < 96u;
  int dx0 = min(max(jx0, 0), 95), dx1 = min(max(jx0 + 1, 0), 95);
  int dy0 = min(max(jy0, 0), 95), dy1 = min(max(jy0 + 1, 0), 95);
  float sw00 = (ux0 && uy0) ? sy0 * sx0 : 0.f;
  float sw10 = (ux1 && uy0) ? sy0 * sx1 : 0.f;
  float sw01 = (ux0 && uy1) ? sy1 * sx0 : 0.f;
  float sw11 = (ux1 && uy1) ? sy1 * sx1 : 0.f;
  int s00 = dy0 * 96 + dx0, s10 = dy0 * 96 + dx1, s01 = dy1 * 96 + dx0, s11 = dy1 * 96 + dx1;
  // ---- P1: gather sta_hr + fea0, 16 channels per thread-group ----
  h8 stv0, stv1, fev0, fev1;
  #pragma unroll
  for (int k = 0; k < 16; k++) {
    int ch = fg * 16 + k;
    const float* xc = x + (size_t)(b * 64 + ch) * 9216;
    float f0 = ww00 * xc[a00] + ww10 * xc[a10] + ww01 * xc[a01] + ww11 * xc[a11];
    const _Float16* sc = sta + (size_t)(b * 64 + ch) * 9216;
    float s0 = sw00 * h2f(sc[s00]) + sw10 * h2f(sc[s10]) + sw01 * h2f(sc[s01]) + sw11 * h2f(sc[s11]);
    if (k < 8) { stv0[k] = f2h(s0); fev0[k] = f2h(f0); }
    else       { stv1[k - 8] = f2h(s0); fev1[k - 8] = f2h(f0); }
  }
  *(h8*)&feat[fswz(px, fg * 16)]          = stv0;
  *(h8*)&feat[fswz(px, fg * 16 + 8)]      = stv1;
  *(h8*)&feat[fswz(px, 64 + fg * 16)]     = fev0;
  *(h8*)&feat[fswz(px, 64 + fg * 16 + 8)] = fev1;
  __syncthreads();
  // ---- P2: t[o] = wcpx[v] . fea0 (both row-variants, select by x parity) ----
  {
    int o2 = fg * 2;
    int v0 = (y & 1) << 1;
    int base = __builtin_amdgcn_readfirstlane((v0 * 8 + o2) * 64);
    const float* w00 = wcpx + base;
    const float* w01 = wcpx + base + 64;
    const float* w10 = wcpx + base + 512;
    const float* w11 = wcpx + base + 512 + 64;
    float acc00 = 0.f, acc01 = 0.f, acc10 = 0.f, acc11 = 0.f;
    #pragma unroll
    for (int cb = 0; cb < 8; cb++) {
      h8 blk = *(const h8*)&feat[fswz(px, 64 + cb * 8)];
      #pragma unroll
      for (int q = 0; q < 8; q++) {
        float fv = h2f(blk[q]);
        int c = cb * 8 + q;
        acc00 = fmaf(w00[c], fv, acc00);
        acc01 = fmaf(w01[c], fv, acc01);
        acc10 = fmaf(w10[c], fv, acc10);
        acc11 = fmaf(w11[c], fv, acc11);
      }
    }
    bool odd = (xg & 1);
    t_lds[o2][px]     = odd ? acc10 : acc00;
    t_lds[o2 + 1][px] = odd ? acc11 : acc01;
  }
  __syncthreads();
  // ---- P3: fea = fea0 + wepx[v] @ t (overwrite fea0 slots) ----
  {
    float tv[8];
    #pragma unroll
    for (int oo = 0; oo < 8; oo++) tv[oo] = t_lds[oo][px];
    int v0 = (y & 1) << 1;
    bool odd = (xg & 1);
    int wbase = __builtin_amdgcn_readfirstlane((v0 * 64 + fg * 16) * 8);
    #pragma unroll
    for (int blki = 0; blki < 2; blki++) {
      h8 f0b = *(const h8*)&feat[fswz(px, 64 + fg * 16 + blki * 8)];
      h8 ob2;
      #pragma unroll
      for (int q = 0; q < 8; q++) {
        int k = blki * 8 + q;
        const float* wA = wepx + wbase + k * 8;
        const float* wB = wA + 512;
        float sA = 0.f, sB = 0.f;
        #pragma unroll
        for (int oo = 0; oo < 8; oo++) { sA = fmaf(wA[oo], tv[oo], sA); sB = fmaf(wB[oo], tv[oo], sB); }
        float fe = h2f(f0b[q]) + (odd ? sB : sA);
        ob2[q] = f2h(fe);
      }
      *(h8*)&feat[fswz(px, 64 + fg * 16 + blki * 8)] = ob2;
    }
  }
  __syncthreads();
  // ---- P4: fusion conv via MFMA: [64px x 128] @ [128 x 64] ----
  {
    int l15 = px & 15, lg = px >> 4;
    h8 af[4];
    #pragma unroll
    for (int ks = 0; ks < 4; ks++)
      af[ks] = *(const h8*)&feat[fswz(fg * 16 + l15, lg * 8 + 32 * ks)];
    #pragma unroll
    for (int Nt = 0; Nt < 4; Nt++) {
      f32x4 acc = {0.f, 0.f, 0.f, 0.f};
      #pragma unroll
      for (int ks = 0; ks < 4; ks++) {
        h8 bfv = *(const h8*)&fusB[((Nt * 4 + ks) * 64 + px) * 8];
        acc = __builtin_amdgcn_mfma_f32_16x16x32_f16(af[ks], bfv, acc, 0, 0, 0);
      }
      int c = Nt * 16 + l15;
      float bias = fusb[c];
      float4 o4;
      o4.x = acc[0] + bias; o4.y = acc[1] + bias; o4.z = acc[2] + bias; o4.w = acc[3] + bias;
      float* op = out + ((size_t)(b * 64 + c) * 192 + y) * 192 + xb * 64 + fg * 16 + lg * 4;
      *(float4*)op = o4;
    }
  }
}

// =====================================================================
extern "C" void kernel_launch(void* const* d_in, const int* in_sizes, int n_in,
                              void* d_out, int out_size, void* d_ws, size_t ws_size,
                              hipStream_t stream)
{
  (void)in_sizes; (void)n_in; (void)out_size; (void)ws_size;
  const float* x    = (const float*)d_in[0];
  const float* st   = (const float*)d_in[1];
  const float* kc_w = (const float*)d_in[2];
  const float* kc_b = (const float*)d_in[3];
  const float* wc   = (const float*)d_in[4];
  const float* we   = (const float*)d_in[5];
  const float* b1w  = (const float*)d_in[6];
  const float* b1b  = (const float*)d_in[7];
  const float* b2w  = (const float*)d_in[8];
  const float* b2b  = (const float*)d_in[9];
  const float* rw   = (const float*)d_in[10];
  const float* rb   = (const float*)d_in[11];
  const float* ow   = (const float*)d_in[12];
  const float* ob   = (const float*)d_in[13];
  const float* sow  = (const float*)d_in[14];
  const float* sob  = (const float*)d_in[15];
  const float* fusw = (const float*)d_in[16];
  const float* fusb = (const float*)d_in[17];
  char* ws = (char*)d_ws;
  _Float16* sta  = (_Float16*)(ws + WS_STA);
  int*   gsi  = (int*)(ws + WS_GSI);
  float* gsf  = (float*)(ws + WS_GSF);
  float* wcpxp = (float*)(ws + WS_WCPX);
  float* wepxp = (float*)(ws + WS_WEPX);
  _Float16* fusB = (_Float16*)(ws + WS_FUSB);
  float* kcbp = (float*)(ws + WS_KCB);
  _Float16* kcw = (_Float16*)(ws + WS_KCW);
  float* outp = (float*)d_out;

  k_prep<<<dim3(100), dim3(256), 0, stream>>>(kc_w, kc_b, fusw, kcw, fusB, kcbp);
  k_embed<<<dim3(1), dim3(256), 0, stream>>>(b1w, b1b, b2w, b2b, rw, rb, ow, ob,
                                             sow, sob, wc, we, gsi, gsf, wcpxp, wepxp);
  k_sta<<<dim3(1152), dim3(256), 0, stream>>>(x, st, kcw, kcbp, sta);
  k_main<<<dim3(2304), dim3(256), 0, stream>>>(x, sta, gsi, gsf, wcpxp, wepxp, fusB, fusb, outp);
}

// Round 4
// 200.224 us; speedup vs baseline: 1.2161x; 1.0671x over previous
//
#include <hip/hip_runtime.h>

// ---------- types ----------
typedef __attribute__((ext_vector_type(8))) _Float16 h8;
typedef __attribute__((ext_vector_type(4))) _Float16 h4;
typedef __attribute__((ext_vector_type(4))) float f32x4;

__device__ __forceinline__ _Float16 f2h(float f) { return (_Float16)f; }
__device__ __forceinline__ float h2f(_Float16 h) { return (float)h; }

// swizzled element index into feat LDS tile [px][128] (XOR of i bits 3..5 with px&7)
__device__ __forceinline__ int fswz(int p, int i) { return p * 128 + (i ^ ((p & 7) << 3)); }

// ---------- ws layout (bytes) ----------
#define WS_STA   0u          // _Float16 [4*64*96*96]            4718592 B
#define WS_GSI   4718592u    // int   [4][4]  {dx,dy,sdx,sdy}
#define WS_GSF   4718656u    // float [4][4]  {wx1,wy1,swx1,swy1}
#define WS_WCPX  4718720u    // float [4][8][64]
#define WS_WEPX  4726912u    // float [4][64][8]
#define WS_FUSB  4735104u    // _Float16 [4][4][64][8]  (fusion B fragments)
#define WS_KCB   4751488u    // float [1600] permuted bias
#define WS_KCW   4757888u    // _Float16 [1600][64] permuted kc_w

// =====================================================================
// k_prep: permute+convert kc_w -> f16 (j' = w*400 + t*16 + cl), permuted
// bias, and fusion-weight B-fragments.
// =====================================================================
__global__ __launch_bounds__(256) void k_prep(
    const float* __restrict__ kc_w, const float* __restrict__ kc_b,
    const float* __restrict__ fusw,
    _Float16* __restrict__ kcw, _Float16* __restrict__ fusB,
    float* __restrict__ kcbp)
{
  int e = blockIdx.x * 256 + threadIdx.x;
  if (e < 25600) {
    int jp = e >> 4, i0 = (e & 15) << 2;
    int w = jp / 400, rem = jp % 400;
    int t = rem >> 4, cl = rem & 15;
    int j = (w * 16 + cl) * 25 + t;           // original row: channel-major c*25+t
    const float4* src = (const float4*)(kc_w + j * 64 + i0);
    float4 v = *src;
    h4 ov;
    ov[0] = f2h(v.x); ov[1] = f2h(v.y); ov[2] = f2h(v.z); ov[3] = f2h(v.w);
    *(h4*)(kcw + jp * 64 + i0) = ov;
  }
  if (e < 8192) {
    // fusB[Nt][ks][lane][j] = fus_w[(Nt*16 + (l&15))*128 + (l>>4)*8 + 32*ks + j]
    int Nt = e >> 11, ks = (e >> 9) & 3, l = (e >> 3) & 63, j = e & 7;
    fusB[e] = f2h(fusw[(Nt * 16 + (l & 15)) * 128 + (l >> 4) * 8 + 32 * ks + j]);
  }
  if (e < 1600) {
    int w = e / 400, rem = e % 400, t = rem >> 4, cl = rem & 15;
    kcbp[e] = kc_b[(w * 16 + cl) * 25 + t];
  }
}

// =====================================================================
// k_embed: the 4 parity variants of the coordinate embedding ->
// grid-sample tables + combined MoE weights.
// =====================================================================
__global__ __launch_bounds__(256) void k_embed(
    const float* __restrict__ b1w, const float* __restrict__ b1b,
    const float* __restrict__ b2w, const float* __restrict__ b2b,
    const float* __restrict__ rw,  const float* __restrict__ rb,
    const float* __restrict__ ow,  const float* __restrict__ ob,
    const float* __restrict__ sow, const float* __restrict__ sob,
    const float* __restrict__ wc,  const float* __restrict__ we,
    int* __restrict__ gs_i, float* __restrict__ gs_f,
    float* __restrict__ wcpx, float* __restrict__ wepx)
{
  __shared__ float l_w2[4096];
  __shared__ float l_h1[4][64];
  __shared__ float l_h2[4][64];
  __shared__ float l_sm[4][8];
  int tid = threadIdx.x;
  for (int e = tid; e < 4096; e += 256) l_w2[e] = b2w[e];
  int g = tid >> 6, o = tid & 63;
  float py = (g >> 1) ? 1.f : 0.f;
  float pxx = (g & 1) ? 1.f : 0.f;
  float chh = (py + 0.5f) * 0.5f;
  float coh = chh - floorf(chh + 0.001f) - 0.5f;
  float cww = (pxx + 0.5f) * 0.5f;
  float cow = cww - floorf(cww + 0.001f) - 0.5f;
  float z = b1b[o] + b1w[o * 4 + 0] * 0.5f + b1w[o * 4 + 1] * 0.5f
          + b1w[o * 4 + 2] * coh + b1w[o * 4 + 3] * cow;
  l_h1[g][o] = fmaxf(z, 0.f);
  __syncthreads();
  float z2 = b2b[o];
  #pragma unroll 8
  for (int i = 0; i < 64; i++) z2 = fmaf(l_w2[o * 64 + i], l_h1[g][i], z2);
  l_h2[g][o] = fmaxf(z2, 0.f);
  __syncthreads();
  if (o < 8) {
    const float* wp; float bias;
    if (o < 4)      { wp = rw  + o * 64;       bias = rb[o]; }
    else if (o < 6) { wp = ow  + (o - 4) * 64; bias = ob[o - 4]; }
    else            { wp = sow + (o - 6) * 64; bias = sob[o - 6]; }
    float acc = bias;
    for (int i = 0; i < 64; i++) acc = fmaf(wp[i], l_h2[g][i], acc);
    if (o < 4) acc = 1.f / (1.f + expf(-acc));
    l_sm[g][o] = acc;
  }
  __syncthreads();
  if (o == 0) {
    float qbx = (g & 1) ? 0.25f : -0.25f;
    float qby = (g >> 1) ? 0.25f : -0.25f;
    float qx  = qbx + l_sm[g][4]; float fx  = floorf(qx);
    float qy  = qby + l_sm[g][5]; float fy  = floorf(qy);
    float qsx = qbx + l_sm[g][6]; float fsx = floorf(qsx);
    float qsy = qby + l_sm[g][7]; float fsy = floorf(qsy);
    gs_i[g * 4 + 0] = (int)fx;  gs_f[g * 4 + 0] = qx - fx;
    gs_i[g * 4 + 1] = (int)fy;  gs_f[g * 4 + 1] = qy - fy;
    gs_i[g * 4 + 2] = (int)fsx; gs_f[g * 4 + 2] = qsx - fsx;
    gs_i[g * 4 + 3] = (int)fsy; gs_f[g * 4 + 3] = qsy - fsy;
  }
  float r0 = l_sm[g][0], r1 = l_sm[g][1], r2 = l_sm[g][2], r3 = l_sm[g][3];
  for (int idx = o; idx < 512; idx += 64) {
    wcpx[g * 512 + idx] = r0 * wc[idx] + r1 * wc[512 + idx] + r2 * wc[1024 + idx] + r3 * wc[1536 + idx];
    wepx[g * 512 + idx] = r0 * we[idx] + r1 * we[512 + idx] + r2 * we[1024 + idx] + r3 * we[1536 + idx];
  }
}

// =====================================================================
// k_sta: fused kernel_warp (f16 MFMA GEMM) + 5x5 spatially-varying conv.
// WG = 256 thr (4 waves), 32-pixel tile (1 row x 32 cols).
// Wave w owns channels [w*16, w*16+16); MFMA D fragment for tap t leaves
// kw[c][px] in lane registers; conv consumes it directly.
// R4: epilogue slice fixed to w*3200 (wave w's OWN x-tile rows: 16ch*5*40).
//     w*6400 in R3 was OOB for w>=2 and raced wave w+1's x rows for w=1.
// =====================================================================
__global__ __launch_bounds__(256, 4) void k_sta(
    const float* __restrict__ x, const float* __restrict__ st,
    const _Float16* __restrict__ kcw, const float* __restrict__ kcbp,
    _Float16* __restrict__ sta_out)
{
  __shared__ __align__(16) _Float16 x_lds[64 * 5 * 40];   // [c][row 0..4][col 0..35 (+pad)]
  __shared__ __align__(16) _Float16 st_lds[32 * 72];      // [px][ch] (+pad)
  int wg = (blockIdx.x & 7) * 144 + (blockIdx.x >> 3);    // XCD-contiguous chunks
  int b = wg / 288;
  int r1 = wg % 288;
  int hb = r1 / 3, wb = r1 % 3;
  int tid = threadIdx.x, lane = tid & 63, w = tid >> 6;
  // ---- stage x tile (5 rows x 36 cols x 64 ch), float4 interior + scalar edges ----
  for (int e = tid; e < 2560; e += 256) {           // interior: cols 2..33
    int row = e >> 3, v = e & 7;                    // row = c*5+rr
    int rr = row % 5;
    int grow = min(max(hb + rr - 2, 0), 95);
    float4 val = *(const float4*)&x[((b * 64 + (row / 5)) * 96 + grow) * 96 + 32 * wb + v * 4];
    _Float16* dst = &x_lds[row * 40 + 2 + v * 4];
    dst[0] = f2h(val.x); dst[1] = f2h(val.y); dst[2] = f2h(val.z); dst[3] = f2h(val.w);
  }
  for (int e = tid; e < 1280; e += 256) {           // edges: cols 0,1,34,35
    int row = e >> 2, j = e & 3;
    int col = (j < 2) ? j : 32 + j;
    int rr = row % 5;
    int grow = min(max(hb + rr - 2, 0), 95);
    int gcol = min(max(32 * wb + col - 2, 0), 95);
    x_lds[row * 40 + col] = f2h(x[((b * 64 + (row / 5)) * 96 + grow) * 96 + gcol]);
  }
  // ---- stage st tile (64 ch x 32 px) coalesced, transposed to [px][ch] ----
  for (int e = tid; e < 512; e += 256) {
    int c = e >> 3, p0 = (e & 7) * 4;
    float4 v = *(const float4*)&st[((size_t)(b * 64 + c) * 96 + hb) * 96 + 32 * wb + p0];
    st_lds[(p0 + 0) * 72 + c] = f2h(v.x);
    st_lds[(p0 + 1) * 72 + c] = f2h(v.y);
    st_lds[(p0 + 2) * 72 + c] = f2h(v.z);
    st_lds[(p0 + 3) * 72 + c] = f2h(v.w);
  }
  __syncthreads();
  // ---- A fragments from LDS: 2 M-subtiles x 2 k-steps ----
  int l15 = lane & 15, lg = lane >> 4;
  h8 afrag[2][2];
  #pragma unroll
  for (int ms = 0; ms < 2; ms++)
    #pragma unroll
    for (int ks = 0; ks < 2; ks++)
      afrag[ms][ks] = *(const h8*)&st_lds[(ms * 16 + l15) * 72 + 32 * ks + lg * 8];
  // ---- main loop: per tap, MFMA kw (stays in regs) -> conv accumulate ----
  float sta_acc[2][4];
  #pragma unroll
  for (int ms = 0; ms < 2; ms++)
    #pragma unroll
    for (int r = 0; r < 4; r++) sta_acc[ms][r] = 0.f;
  for (int dh = 0; dh < 5; dh++) {
    h4 xa[2][2];   // per ms: 8 contiguous h16 at cols [ms*16+lg*4 .. +7]
    #pragma unroll
    for (int ms = 0; ms < 2; ms++) {
      const _Float16* xp = &x_lds[((w * 16 + l15) * 5 + dh) * 40 + ms * 16 + lg * 4];
      xa[ms][0] = *(const h4*)xp;
      xa[ms][1] = *(const h4*)(xp + 4);
    }
    #pragma unroll
    for (int dw = 0; dw < 5; dw++) {
      int jbase = w * 400 + (dh * 5 + dw) * 16;
      const _Float16* bp = kcw + (jbase + l15) * 64 + lg * 8;
      h8 bf0 = *(const h8*)bp;
      h8 bf1 = *(const h8*)(bp + 32);
      float kb = kcbp[jbase + l15];
      #pragma unroll
      for (int ms = 0; ms < 2; ms++) {
        f32x4 acc = {0.f, 0.f, 0.f, 0.f};
        acc = __builtin_amdgcn_mfma_f32_16x16x32_f16(afrag[ms][0], bf0, acc, 0, 0, 0);
        acc = __builtin_amdgcn_mfma_f32_16x16x32_f16(afrag[ms][1], bf1, acc, 0, 0, 0);
        #pragma unroll
        for (int r = 0; r < 4; r++) {
          float kw = acc[r] + kb;
          kw = (kw >= 0.f) ? kw : 0.1f * kw;      // leaky_relu 0.1 (kw stays f32)
          int ci = r + dw;                        // static after unroll
          float xvf = h2f(ci < 4 ? xa[ms][0][ci] : xa[ms][1][ci - 4]);
          sta_acc[ms][r] = fmaf(kw, xvf, sta_acc[ms][r]);
        }
      }
    }
  }
  // ---- epilogue: transpose via wave-private x_lds slice -> full-line stores ----
  // wave w's slice = its own channel rows [w*3200, w*3200+3200); only wave w
  // ever touches them (main-loop reads were by wave w) -> race-free, no barrier.
  {
    _Float16* lds2 = &x_lds[w * 3200];              // [16 ch][36] h16 used
    #pragma unroll
    for (int ms = 0; ms < 2; ms++) {
      h4 ov;
      #pragma unroll
      for (int r = 0; r < 4; r++) ov[r] = f2h(sta_acc[ms][r]);
      *(h4*)&lds2[l15 * 36 + ms * 16 + lg * 4] = ov;   // same-wave order: safe
    }
    int ch = lane >> 2, q = lane & 3;
    h4 lo = *(const h4*)&lds2[ch * 36 + q * 8];
    h4 hi = *(const h4*)&lds2[ch * 36 + q * 8 + 4];
    h8 ov;
    #pragma unroll
    for (int r = 0; r < 4; r++) { ov[r] = lo[r]; ov[r + 4] = hi[r]; }
    *(h8*)(sta_out + ((size_t)(b * 64 + w * 16 + ch) * 96 + hb) * 96 + 32 * wb + q * 8) = ov;
  }
}

// =====================================================================
// k_main: per 64-pixel HR row chunk: grid samples (parity-table stencils),
// MoE (precombined weights, scalar-load), fusion conv via f16 MFMA.
// R3: XCD-aware block swizzle.
// =====================================================================
__global__ __launch_bounds__(256) void k_main(
    const float* __restrict__ x, const _Float16* __restrict__ sta,
    const int* __restrict__ gs_i, const float* __restrict__ gs_f,
    const float* __restrict__ wcpx, const float* __restrict__ wepx,
    const _Float16* __restrict__ fusB, const float* __restrict__ fusb,
    float* __restrict__ out)
{
  __shared__ __align__(16) _Float16 feat[64 * 128]; // swizzled [px][0:64 sta_hr | 64:128 fea0->fea]
  __shared__ float t_lds[8][68];
  int wg = (blockIdx.x & 7) * 288 + (blockIdx.x >> 3);  // XCD-contiguous chunks
  int b = wg / 576, r = wg % 576;
  int y = r / 3, xb = r % 3;
  int tid = threadIdx.x, px = tid & 63, fg = tid >> 6;
  int xg = xb * 64 + px;
  int v = ((y & 1) << 1) | (xg & 1);
  int idxo = gs_i[v * 4 + 0], idyo = gs_i[v * 4 + 1], idxs = gs_i[v * 4 + 2], idys = gs_i[v * 4 + 3];
  float wx1 = gs_f[v * 4 + 0], wy1 = gs_f[v * 4 + 1], sx1 = gs_f[v * 4 + 2], sy1 = gs_f[v * 4 + 3];
  int xh = xg >> 1, yh = y >> 1;
  // offset path (fea0 from x)
  int ix0 = xh + idxo, iy0 = yh + idyo;
  float wx0 = 1.f - wx1, wy0 = 1.f - wy1;
  bool vx0 = (unsigned)ix0 < 96u, vx1 = (unsigned)(ix0 + 1) < 96u;
  bool vy0 = (unsigned)iy0 < 96u, vy1 = (unsigned)(iy0 + 1) < 96u;
  int cx0 = min(max(ix0, 0), 95), cx1 = min(max(ix0 + 1, 0), 95);
  int cy0 = min(max(iy0, 0), 95), cy1 = min(max(iy0 + 1, 0), 95);
  float ww00 = (vx0 && vy0) ? wy0 * wx0 : 0.f;
  float ww10 = (vx1 && vy0) ? wy0 * wx1 : 0.f;
  float ww01 = (vx0 && vy1) ? wy1 * wx0 : 0.f;
  float ww11 = (vx1 && vy1) ? wy1 * wx1 : 0.f;
  int a00 = cy0 * 96 + cx0, a10 = cy0 * 96 + cx1, a01 = cy1 * 96 + cx0, a11 = cy1 * 96 + cx1;
  // st_offset path (sta_hr from sta_feat)
  int jx0 = xh + idxs, jy0 = yh + idys;
  float sx0 = 1.f - sx1, sy0 = 1.f - sy1;
  bool ux0 = (unsigned)jx0 < 96u, ux1 = (unsigned)(jx0 + 1) < 96u;
  bool uy0 = (unsigned)jy0 < 96u, uy1 = (unsigned)(jy0 + 1) < 96u;
  int dx0 = min(max(jx0, 0), 95), dx1 = min(max(jx0 + 1, 0), 95);
  int dy0 = min(max(jy0, 0), 95), dy1 = min(max(jy0 + 1, 0), 95);
  float sw00 = (ux0 && uy0) ? sy0 * sx0 : 0.f;
  float sw10 = (ux1 && uy0) ? sy0 * sx1 : 0.f;
  float sw01 = (ux0 && uy1) ? sy1 * sx0 : 0.f;
  float sw11 = (ux1 && uy1) ? sy1 * sx1 : 0.f;
  int s00 = dy0 * 96 + dx0, s10 = dy0 * 96 + dx1, s01 = dy1 * 96 + dx0, s11 = dy1 * 96 + dx1;
  // ---- P1: gather sta_hr + fea0, 16 channels per thread-group ----
  h8 stv0, stv1, fev0, fev1;
  #pragma unroll
  for (int k = 0; k < 16; k++) {
    int ch = fg * 16 + k;
    const float* xc = x + (size_t)(b * 64 + ch) * 9216;
    float f0 = ww00 * xc[a00] + ww10 * xc[a10] + ww01 * xc[a01] + ww11 * xc[a11];
    const _Float16* sc = sta + (size_t)(b * 64 + ch) * 9216;
    float s0 = sw00 * h2f(sc[s00]) + sw10 * h2f(sc[s10]) + sw01 * h2f(sc[s01]) + sw11 * h2f(sc[s11]);
    if (k < 8) { stv0[k] = f2h(s0); fev0[k] = f2h(f0); }
    else       { stv1[k - 8] = f2h(s0); fev1[k - 8] = f2h(f0); }
  }
  *(h8*)&feat[fswz(px, fg * 16)]          = stv0;
  *(h8*)&feat[fswz(px, fg * 16 + 8)]      = stv1;
  *(h8*)&feat[fswz(px, 64 + fg * 16)]     = fev0;
  *(h8*)&feat[fswz(px, 64 + fg * 16 + 8)] = fev1;
  __syncthreads();
  // ---- P2: t[o] = wcpx[v] . fea0 (both row-variants, select by x parity) ----
  {
    int o2 = fg * 2;
    int v0 = (y & 1) << 1;
    int base = __builtin_amdgcn_readfirstlane((v0 * 8 + o2) * 64);
    const float* w00 = wcpx + base;
    const float* w01 = wcpx + base + 64;
    const float* w10 = wcpx + base + 512;
    const float* w11 = wcpx + base + 512 + 64;
    float acc00 = 0.f, acc01 = 0.f, acc10 = 0.f, acc11 = 0.f;
    #pragma unroll
    for (int cb = 0; cb < 8; cb++) {
      h8 blk = *(const h8*)&feat[fswz(px, 64 + cb * 8)];
      #pragma unroll
      for (int q = 0; q < 8; q++) {
        float fv = h2f(blk[q]);
        int c = cb * 8 + q;
        acc00 = fmaf(w00[c], fv, acc00);
        acc01 = fmaf(w01[c], fv, acc01);
        acc10 = fmaf(w10[c], fv, acc10);
        acc11 = fmaf(w11[c], fv, acc11);
      }
    }
    bool odd = (xg & 1);
    t_lds[o2][px]     = odd ? acc10 : acc00;
    t_lds[o2 + 1][px] = odd ? acc11 : acc01;
  }
  __syncthreads();
  // ---- P3: fea = fea0 + wepx[v] @ t (overwrite fea0 slots) ----
  {
    float tv[8];
    #pragma unroll
    for (int oo = 0; oo < 8; oo++) tv[oo] = t_lds[oo][px];
    int v0 = (y & 1) << 1;
    bool odd = (xg & 1);
    int wbase = __builtin_amdgcn_readfirstlane((v0 * 64 + fg * 16) * 8);
    #pragma unroll
    for (int blki = 0; blki < 2; blki++) {
      h8 f0b = *(const h8*)&feat[fswz(px, 64 + fg * 16 + blki * 8)];
      h8 ob2;
      #pragma unroll
      for (int q = 0; q < 8; q++) {
        int k = blki * 8 + q;
        const float* wA = wepx + wbase + k * 8;
        const float* wB = wA + 512;
        float sA = 0.f, sB = 0.f;
        #pragma unroll
        for (int oo = 0; oo < 8; oo++) { sA = fmaf(wA[oo], tv[oo], sA); sB = fmaf(wB[oo], tv[oo], sB); }
        float fe = h2f(f0b[q]) + (odd ? sB : sA);
        ob2[q] = f2h(fe);
      }
      *(h8*)&feat[fswz(px, 64 + fg * 16 + blki * 8)] = ob2;
    }
  }
  __syncthreads();
  // ---- P4: fusion conv via MFMA: [64px x 128] @ [128 x 64] ----
  {
    int l15 = px & 15, lg = px >> 4;
    h8 af[4];
    #pragma unroll
    for (int ks = 0; ks < 4; ks++)
      af[ks] = *(const h8*)&feat[fswz(fg * 16 + l15, lg * 8 + 32 * ks)];
    #pragma unroll
    for (int Nt = 0; Nt < 4; Nt++) {
      f32x4 acc = {0.f, 0.f, 0.f, 0.f};
      #pragma unroll
      for (int ks = 0; ks < 4; ks++) {
        h8 bfv = *(const h8*)&fusB[((Nt * 4 + ks) * 64 + px) * 8];
        acc = __builtin_amdgcn_mfma_f32_16x16x32_f16(af[ks], bfv, acc, 0, 0, 0);
      }
      int c = Nt * 16 + l15;
      float bias = fusb[c];
      float4 o4;
      o4.x = acc[0] + bias; o4.y = acc[1] + bias; o4.z = acc[2] + bias; o4.w = acc[3] + bias;
      float* op = out + ((size_t)(b * 64 + c) * 192 + y) * 192 + xb * 64 + fg * 16 + lg * 4;
      *(float4*)op = o4;
    }
  }
}

// =====================================================================
extern "C" void kernel_launch(void* const* d_in, const int* in_sizes, int n_in,
                              void* d_out, int out_size, void* d_ws, size_t ws_size,
                              hipStream_t stream)
{
  (void)in_sizes; (void)n_in; (void)out_size; (void)ws_size;
  const float* x    = (const float*)d_in[0];
  const float* st   = (const float*)d_in[1];
  const float* kc_w = (const float*)d_in[2];
  const float* kc_b = (const float*)d_in[3];
  const float* wc   = (const float*)d_in[4];
  const float* we   = (const float*)d_in[5];
  const float* b1w  = (const float*)d_in[6];
  const float* b1b  = (const float*)d_in[7];
  const float* b2w  = (const float*)d_in[8];
  const float* b2b  = (const float*)d_in[9];
  const float* rw   = (const float*)d_in[10];
  const float* rb   = (const float*)d_in[11];
  const float* ow   = (const float*)d_in[12];
  const float* ob   = (const float*)d_in[13];
  const float* sow  = (const float*)d_in[14];
  const float* sob  = (const float*)d_in[15];
  const float* fusw = (const float*)d_in[16];
  const float* fusb = (const float*)d_in[17];
  char* ws = (char*)d_ws;
  _Float16* sta  = (_Float16*)(ws + WS_STA);
  int*   gsi  = (int*)(ws + WS_GSI);
  float* gsf  = (float*)(ws + WS_GSF);
  float* wcpxp = (float*)(ws + WS_WCPX);
  float* wepxp = (float*)(ws + WS_WEPX);
  _Float16* fusB = (_Float16*)(ws + WS_FUSB);
  float* kcbp = (float*)(ws + WS_KCB);
  _Float16* kcw = (_Float16*)(ws + WS_KCW);
  float* outp = (float*)d_out;

  k_prep<<<dim3(100), dim3(256), 0, stream>>>(kc_w, kc_b, fusw, kcw, fusB, kcbp);
  k_embed<<<dim3(1), dim3(256), 0, stream>>>(b1w, b1b, b2w, b2b, rw, rb, ow, ob,
                                             sow, sob, wc, we, gsi, gsf, wcpxp, wepxp);
  k_sta<<<dim3(1152), dim3(256), 0, stream>>>(x, st, kcw, kcbp, sta);
  k_main<<<dim3(2304), dim3(256), 0, stream>>>(x, sta, gsi, gsf, wcpxp, wepxp, fusB, fusb, outp);
}